// Round 5
// baseline (318.832 us; speedup 1.0000x reference)
//
#include <hip/hip_runtime.h>

// ---------------------------------------------------------------------------
// Problem constants
// ---------------------------------------------------------------------------
#define V_PREV 16384
#define V_NEXT 65536
#define F_IN   512
#define F_OUT  256
#define NNZ_UP 65536
#define N_EDGE 524288

using f32x4 = __attribute__((ext_vector_type(4))) float;
using bfrag = __attribute__((ext_vector_type(8))) short;   // 8 x bf16

__device__ __forceinline__ ushort f2bf(float f) {
    union { float f; unsigned u; } v; v.f = f;
    unsigned r = (v.u + 0x7FFFu + ((v.u >> 16) & 1u)) >> 16;
    return (ushort)r;
}
__device__ __forceinline__ float bf2f(ushort h) {
    union { unsigned u; float f; } v; v.u = ((unsigned)h) << 16; return v.f;
}

// ---------------------------------------------------------------------------
// Weight prep (transpose + bf16, concat Uj|Ui; bias1 Ui-half folds b_res)
// ---------------------------------------------------------------------------
__global__ void prep_weights_kernel(const float* __restrict__ Wres,
                                    const float* __restrict__ Ui0W, const float* __restrict__ Uj0W,
                                    const float* __restrict__ Ui1W, const float* __restrict__ Uj1W,
                                    const float* __restrict__ Ui1b, const float* __restrict__ Uj1b,
                                    const float* __restrict__ bres,
                                    ushort* __restrict__ WresT, ushort* __restrict__ W0t,
                                    ushort* __restrict__ W1t, float* __restrict__ bias1)
{
    int i = blockIdx.x * blockDim.x + threadIdx.x;   // 0 .. 512*512-1
    if (i < 256 * 512) {
        int n = i / 512, k = i % 512;
        WresT[i] = f2bf(Wres[k * 256 + n]);
    }
    if (i < 512 * 512) {
        int n = i / 512, k = i % 512;
        W0t[i] = f2bf(n < 256 ? Uj0W[k * 256 + n] : Ui0W[k * 256 + (n - 256)]);
    }
    if (i < 512 * 256) {
        int n = i / 256, k = i % 256;
        W1t[i] = f2bf(n < 256 ? Uj1W[k * 256 + n] : Ui1W[k * 256 + (n - 256)]);
    }
    if (i < 512) bias1[i] = (i < 256) ? Uj1b[i] : (Ui1b[i - 256] + bres[i - 256]);
}

// ---------------------------------------------------------------------------
// CSR build: histogram -> 2-level exclusive scan -> fill (dst-sorted src/val)
// ---------------------------------------------------------------------------
__global__ void hist_kernel(const int* __restrict__ dst, int* __restrict__ cnt) {
    int e = blockIdx.x * blockDim.x + threadIdx.x;
    atomicAdd(&cnt[dst[e]], 1);
}

__global__ void scan_block_kernel(const int* __restrict__ cnt, int* __restrict__ offs,
                                  int* __restrict__ bsum)
{
    __shared__ int buf[2][256];
    int t = threadIdx.x;
    int i = blockIdx.x * 256 + t;
    int v = cnt[i];
    int p = 0;
    buf[0][t] = v;
    __syncthreads();
    for (int d = 1; d < 256; d <<= 1) {
        int nv = buf[p][t] + ((t >= d) ? buf[p][t - d] : 0);
        buf[p ^ 1][t] = nv;
        p ^= 1;
        __syncthreads();
    }
    int incl = buf[p][t];
    offs[i] = incl - v;
    if (t == 255) bsum[blockIdx.x] = incl;
}

__global__ void scan_top_kernel(const int* __restrict__ bsum, int* __restrict__ boff)
{
    __shared__ int buf[2][256];
    int t = threadIdx.x;
    int v = bsum[t];
    int p = 0;
    buf[0][t] = v;
    __syncthreads();
    for (int d = 1; d < 256; d <<= 1) {
        int nv = buf[p][t] + ((t >= d) ? buf[p][t - d] : 0);
        buf[p ^ 1][t] = nv;
        p ^= 1;
        __syncthreads();
    }
    boff[t] = buf[p][t] - v;
}

__global__ void add_offs_kernel(int* __restrict__ offs, const int* __restrict__ boff,
                                int* __restrict__ cursor)
{
    int i = blockIdx.x * 256 + threadIdx.x;
    int o = offs[i] + boff[blockIdx.x];
    offs[i] = o;
    cursor[i] = o;
}

__global__ void fill_kernel(const int* __restrict__ src, const int* __restrict__ dst,
                            const float* __restrict__ adjv,
                            int* __restrict__ cursor, int* __restrict__ srcs,
                            float* __restrict__ vals)
{
    int e = blockIdx.x * blockDim.x + threadIdx.x;
    int d = dst[e];
    int p = atomicAdd(&cursor[d], 1);
    srcs[p] = src[e];
    vals[p] = adjv[e];
}

// Invert the up map: colof[up_row[k]] = up_col[k], valof[up_row[k]] = up_val[k]
__global__ void invert_up_kernel(const int* __restrict__ up_row, const int* __restrict__ up_col,
                                 const float* __restrict__ up_val,
                                 int* __restrict__ colof, float* __restrict__ valof)
{
    int k = blockIdx.x * blockDim.x + threadIdx.x;
    int r = up_row[k];
    colof[r] = up_col[k];
    valof[r] = up_val[k];
}

// ---------------------------------------------------------------------------
// BatchNorm stats
// ---------------------------------------------------------------------------
__global__ void bn0_part_kernel(const float* __restrict__ x,
                                float* __restrict__ psum, float* __restrict__ psq)
{
    int blk = blockIdx.x, t = threadIdx.x;
    float s0 = 0, s1 = 0, q0 = 0, q1 = 0;
    for (int r = 0; r < 128; r++) {
        size_t base = ((size_t)blk * 128 + r) * 512;
        float a = x[base + t], b = x[base + t + 256];
        s0 += a; q0 += a * a; s1 += b; q1 += b * b;
    }
    psum[blk * 512 + t] = s0; psum[blk * 512 + t + 256] = s1;
    psq [blk * 512 + t] = q0; psq [blk * 512 + t + 256] = q1;
}

// X1 bf16 [65536,256]; 512 blocks x 128 rows
__global__ void bn1_part_bf16_kernel(const ushort* __restrict__ xx,
                                     float* __restrict__ psum, float* __restrict__ psq)
{
    int blk = blockIdx.x, t = threadIdx.x;
    float s = 0, q = 0;
    for (int r = 0; r < 128; r++) {
        float a = bf2f(xx[((size_t)blk * 128 + r) * 256 + t]);
        s += a; q += a * a;
    }
    psum[blk * 256 + t] = s; psq[blk * 256 + t] = q;
}

// Parallel finish: one wave per channel
__global__ void bn_finish_kernel(const float* __restrict__ psum, const float* __restrict__ psq,
                                 int nblocks, int C, float invN,
                                 const float* __restrict__ g, const float* __restrict__ b,
                                 float* __restrict__ sc, float* __restrict__ sh)
{
    int gw = (blockIdx.x * blockDim.x + threadIdx.x) >> 6;   // channel
    int lane = threadIdx.x & 63;
    if (gw >= C) return;
    float s = 0, q = 0;
    for (int i = lane; i < nblocks; i += 64) {
        s += psum[(size_t)i * C + gw];
        q += psq [(size_t)i * C + gw];
    }
#pragma unroll
    for (int d = 32; d > 0; d >>= 1) {
        s += __shfl_xor(s, d);
        q += __shfl_xor(q, d);
    }
    if (lane == 0) {
        float m = s * invN;
        float v = q * invN - m * m;
        float r = rsqrtf(v + 1e-5f);
        float scale = r * g[gw];
        sc[gw] = scale;
        sh[gw] = b[gw] - m * scale;
    }
}

// ---------------------------------------------------------------------------
// GEMM0 fused: reads x f32 [16384,512] directly.
//   blocks bx<2:  XW  = bf16(x) @ WresT^T          (raw A)
//   blocks bx>=2: XNU = bf16(relu(bn0(x))) @ W0t^T (bn A)
// 128x128 tile, BK=32, pad 72 shorts (bank period 8 -> ~2-way, free)
// ---------------------------------------------------------------------------
__global__ __launch_bounds__(256)
void gemm0_fused_kernel(const float* __restrict__ x,
                        const ushort* __restrict__ WresT, const ushort* __restrict__ W0t,
                        const float* __restrict__ sc0, const float* __restrict__ sh0,
                        ushort* __restrict__ XW, ushort* __restrict__ XNU)
{
    __shared__ ushort As[128 * 72];
    __shared__ ushort Bs[128 * 72];
    __shared__ float s_sc[512], s_sh[512];

    const int tid = threadIdx.x;
    const bool bnmode = blockIdx.x >= 2;
    const ushort* Bt = bnmode ? W0t : WresT;
    const int tN  = blockIdx.x * 128;
    const int tNl = bnmode ? tN - 256 : tN;
    const int Nout = bnmode ? 512 : 256;
    ushort* Cout = bnmode ? XNU : XW;
    const int tM = blockIdx.y * 128;

    for (int i = tid; i < 512; i += 256) { s_sc[i] = sc0[i]; s_sh[i] = sh0[i]; }
    __syncthreads();

    const int lane = tid & 63;
    const int wave = tid >> 6;
    const int wm = wave >> 1, wn = wave & 1;
    const int lr = lane & 15, lg = lane >> 4;

    const int ra = tid >> 1;            // A-stage row 0..127
    const int sa = (tid & 1) * 16;      // A-stage col 0 or 16
    const int rb = tid >> 2;            // B-stage row 0..63
    const int sb = (tid & 3) * 8;       // B-stage col 0,8,16,24

    f32x4 acc[4][4] = {};

    for (int k0 = 0; k0 < 512; k0 += 32) {
        // --- A stage: 16 f32 -> bf16 (optional bn+relu) ---
        const float* xp = &x[(size_t)(tM + ra) * 512 + k0 + sa];
        float4 f0 = *(const float4*)(xp);
        float4 f1 = *(const float4*)(xp + 4);
        float4 f2 = *(const float4*)(xp + 8);
        float4 f3 = *(const float4*)(xp + 12);
        float vv[16] = { f0.x,f0.y,f0.z,f0.w, f1.x,f1.y,f1.z,f1.w,
                         f2.x,f2.y,f2.z,f2.w, f3.x,f3.y,f3.z,f3.w };
        ushort hh[16];
        if (bnmode) {
#pragma unroll
            for (int j = 0; j < 16; j++) {
                int c = k0 + sa + j;
                hh[j] = f2bf(fmaxf(vv[j] * s_sc[c] + s_sh[c], 0.0f));
            }
        } else {
#pragma unroll
            for (int j = 0; j < 16; j++) hh[j] = f2bf(vv[j]);
        }
        *(uint4*)&As[ra * 72 + sa]     = *(uint4*)&hh[0];
        *(uint4*)&As[ra * 72 + sa + 8] = *(uint4*)&hh[8];

        // --- B stage ---
        *(uint4*)&Bs[(rb     ) * 72 + sb] = *(const uint4*)&Bt[(size_t)(tNl + rb     ) * 512 + k0 + sb];
        *(uint4*)&Bs[(rb + 64) * 72 + sb] = *(const uint4*)&Bt[(size_t)(tNl + rb + 64) * 512 + k0 + sb];
        __syncthreads();

        bfrag af[4], bfv[4];
#pragma unroll
        for (int mm = 0; mm < 4; mm++)
            af[mm] = *(const bfrag*)&As[(wm * 64 + mm * 16 + lr) * 72 + lg * 8];
#pragma unroll
        for (int nn = 0; nn < 4; nn++)
            bfv[nn] = *(const bfrag*)&Bs[(wn * 64 + nn * 16 + lr) * 72 + lg * 8];
#pragma unroll
        for (int mm = 0; mm < 4; mm++)
#pragma unroll
            for (int nn = 0; nn < 4; nn++)
                acc[mm][nn] = __builtin_amdgcn_mfma_f32_16x16x32_bf16(af[mm], bfv[nn], acc[mm][nn], 0, 0, 0);
        __syncthreads();
    }

#pragma unroll
    for (int mm = 0; mm < 4; mm++)
#pragma unroll
        for (int nn = 0; nn < 4; nn++)
#pragma unroll
            for (int r = 0; r < 4; r++) {
                int row = tM + wm * 64 + mm * 16 + lg * 4 + r;
                int col = tNl + wn * 64 + nn * 16 + lr;
                Cout[(size_t)row * Nout + col] = f2bf(acc[mm][nn][r]);
            }
}

// ---------------------------------------------------------------------------
// GEMM1 panel: one block per 128-row M-slab; A = relu(bn1(X1)) staged ONCE
// into a full-K (256) LDS panel (XOR-swizzled 16B units); loops the 4 N-tiles
// of W1t streaming 64-wide B chunks. Epilogue:
//   nt 0,1 -> YJ  (bf16) = A @ Uj1 + Uj1_b
//   nt 2,3 -> UIb (bf16) = A @ Ui1 + (Ui1_b + b_res) + up_val*XW[up_col]
// Dynamic LDS: Ap 64KB + Bp 16KB = 80KB -> 2 blocks/CU.
// ---------------------------------------------------------------------------
__global__ __launch_bounds__(256)
void gemm1_panel_kernel(const ushort* __restrict__ X1, const ushort* __restrict__ W1t,
                        const float* __restrict__ sc1, const float* __restrict__ sh1,
                        const float* __restrict__ bias1,
                        const int* __restrict__ colof, const float* __restrict__ valof,
                        const ushort* __restrict__ XW,
                        ushort* __restrict__ YJ, ushort* __restrict__ UIb)
{
    extern __shared__ char smem[];
    ushort* Ap = (ushort*)smem;                 // [128][256] bf16, swizzled
    ushort* Bp = (ushort*)(smem + 65536);       // [128][64]  bf16, swizzled
    float* s_sc = (float*)Bp;                   // staged in Bp region (dead after A stage)
    float* s_sh = (float*)(smem + 65536 + 1024);

    const int tid = threadIdx.x;
    const int tM = blockIdx.x * 128;

    if (tid < 256) { s_sc[tid] = sc1[tid]; s_sh[tid] = sh1[tid]; }
    __syncthreads();

    // ---- A panel stage: 128 rows x 32 units (16B), bn+relu applied ----
#pragma unroll
    for (int i = 0; i < 16; i++) {
        int idx = tid + i * 256;            // 0..4095
        int row = idx >> 5;
        int u   = idx & 31;
        ushort h[8], d[8];
        *(uint4*)h = *(const uint4*)&X1[(size_t)(tM + row) * 256 + u * 8];
#pragma unroll
        for (int j = 0; j < 8; j++) {
            int c = u * 8 + j;
            d[j] = f2bf(fmaxf(bf2f(h[j]) * s_sc[c] + s_sh[c], 0.0f));
        }
        int su = u ^ (row & 7);
        *(uint4*)&Ap[row * 256 + su * 8] = *(uint4*)d;
    }

    const int lane = tid & 63;
    const int wave = tid >> 6;
    const int wm = wave >> 1, wn = wave & 1;
    const int lr = lane & 15, lg = lane >> 4;

    for (int nt = 0; nt < 4; nt++) {
        f32x4 acc[4][4] = {};
        for (int kc = 0; kc < 4; kc++) {
            __syncthreads();   // Bp free (prev readers done / sc,sh dead)
            // ---- B chunk stage: rows of W1t tile nt, k = kc*64..+64 ----
#pragma unroll
            for (int i = 0; i < 4; i++) {
                int idx = tid + i * 256;    // 0..1023
                int row = idx >> 3;
                int u   = idx & 7;
                int su  = u ^ (row & 7);
                *(uint4*)&Bp[row * 64 + su * 8] =
                    *(const uint4*)&W1t[(size_t)(nt * 128 + row) * 256 + kc * 64 + u * 8];
            }
            __syncthreads();
#pragma unroll
            for (int ks = 0; ks < 2; ks++) {
                bfrag af[4], bfv[4];
#pragma unroll
                for (int mm = 0; mm < 4; mm++) {
                    int row = wm * 64 + mm * 16 + lr;
                    int gu  = kc * 8 + ks * 4 + lg;
                    int su  = gu ^ (row & 7);
                    af[mm] = *(const bfrag*)&Ap[row * 256 + su * 8];
                }
#pragma unroll
                for (int nn = 0; nn < 4; nn++) {
                    int row = wn * 64 + nn * 16 + lr;
                    int u   = ks * 4 + lg;
                    int su  = u ^ (row & 7);
                    bfv[nn] = *(const bfrag*)&Bp[row * 64 + su * 8];
                }
#pragma unroll
                for (int mm = 0; mm < 4; mm++)
#pragma unroll
                    for (int nn = 0; nn < 4; nn++)
                        acc[mm][nn] = __builtin_amdgcn_mfma_f32_16x16x32_bf16(af[mm], bfv[nn], acc[mm][nn], 0, 0, 0);
            }
        }
        // ---- epilogue for this N-tile ----
        if (nt < 2) {
#pragma unroll
            for (int mm = 0; mm < 4; mm++)
#pragma unroll
                for (int nn = 0; nn < 4; nn++)
#pragma unroll
                    for (int r = 0; r < 4; r++) {
                        int row = tM + wm * 64 + mm * 16 + lg * 4 + r;
                        int col = nt * 128 + wn * 64 + nn * 16 + lr;
                        YJ[(size_t)row * 256 + col] = f2bf(acc[mm][nn][r] + bias1[col]);
                    }
        } else {
#pragma unroll
            for (int mm = 0; mm < 4; mm++) {
#pragma unroll
                for (int r = 0; r < 4; r++) {
                    int row = tM + wm * 64 + mm * 16 + lg * 4 + r;
                    int c = colof[row];
                    float s = valof[row];
#pragma unroll
                    for (int nn = 0; nn < 4; nn++) {
                        int col2 = (nt - 2) * 128 + wn * 64 + nn * 16 + lr;
                        float v = acc[mm][nn][r] + bias1[256 + col2]
                                + s * bf2f(XW[(size_t)c * 256 + col2]);
                        UIb[(size_t)row * 256 + col2] = f2bf(v);
                    }
                }
            }
        }
    }
}

// ---------------------------------------------------------------------------
// up UJ table: UJb[r] = bf16(uj0_b + valof[r] * XNU[colof[r], 0:256])
// ---------------------------------------------------------------------------
__global__ __launch_bounds__(256)
void up_uj_kernel(const int* __restrict__ colof, const float* __restrict__ valof,
                  const ushort* __restrict__ XNU, const float* __restrict__ uj_b,
                  ushort* __restrict__ UJb)
{
    int k = blockIdx.x * 4 + (threadIdx.x >> 6);
    int f = (threadIdx.x & 63) * 4;
    int c = colof[k];
    float s = valof[k];
    ushort4 u = *(const ushort4*)&XNU[(size_t)c * 512 + f];
    const ushort* up = (const ushort*)&u;
    ushort o[4];
#pragma unroll
    for (int j = 0; j < 4; j++) o[j] = f2bf(uj_b[f + j] + s * bf2f(up[j]));
    *(ushort4*)&UJb[(size_t)k * 256 + f] = make_ushort4(o[0], o[1], o[2], o[3]);
}

// ---------------------------------------------------------------------------
// Gather layer 0: X1[d] = (ui0_b + valof[d]*XNU[colof[d],256:512]) + sum val*UJb[src]
// ---------------------------------------------------------------------------
__global__ __launch_bounds__(256)
void gather0_kernel(const int* __restrict__ offs, const int* __restrict__ cnt,
                    const int* __restrict__ srcs, const float* __restrict__ vals,
                    const int* __restrict__ colof, const float* __restrict__ valof,
                    const ushort* __restrict__ XNU, const float* __restrict__ ui_b,
                    const ushort* __restrict__ UJb, ushort* __restrict__ X1)
{
    int d = blockIdx.x * 4 + (threadIdx.x >> 6);
    int f = (threadIdx.x & 63) * 4;
    int c = colof[d];
    float s = valof[d];
    ushort4 u = *(const ushort4*)&XNU[(size_t)c * 512 + 256 + f];
    const ushort* up = (const ushort*)&u;
    float a0 = ui_b[f + 0] + s * bf2f(up[0]);
    float a1 = ui_b[f + 1] + s * bf2f(up[1]);
    float a2 = ui_b[f + 2] + s * bf2f(up[2]);
    float a3 = ui_b[f + 3] + s * bf2f(up[3]);

    int st = offs[d], n = cnt[d];
    if (n > 0) {
        int   sc = srcs[st];
        float ac = vals[st];
        ushort4 vc = *(const ushort4*)&UJb[(size_t)sc * 256 + f];
        for (int e = 1; e < n; e++) {
            int   sn = srcs[st + e];
            float an = vals[st + e];
            ushort4 vn = *(const ushort4*)&UJb[(size_t)sn * 256 + f];
            const ushort* vp = (const ushort*)&vc;
            a0 += ac * bf2f(vp[0]); a1 += ac * bf2f(vp[1]);
            a2 += ac * bf2f(vp[2]); a3 += ac * bf2f(vp[3]);
            vc = vn; ac = an;
        }
        const ushort* vp = (const ushort*)&vc;
        a0 += ac * bf2f(vp[0]); a1 += ac * bf2f(vp[1]);
        a2 += ac * bf2f(vp[2]); a3 += ac * bf2f(vp[3]);
    }
    *(ushort4*)&X1[(size_t)d * 256 + f] =
        make_ushort4(f2bf(a0), f2bf(a1), f2bf(a2), f2bf(a3));
}

// ---------------------------------------------------------------------------
// Gather layer 1: out[d] = bf2f(UIb[d]) + sum val*YJ[src]   (single write)
// ---------------------------------------------------------------------------
__global__ __launch_bounds__(256)
void gather1_kernel(const int* __restrict__ offs, const int* __restrict__ cnt,
                    const int* __restrict__ srcs, const float* __restrict__ vals,
                    const ushort* __restrict__ YJ, const ushort* __restrict__ UIb,
                    float* __restrict__ out)
{
    int d = blockIdx.x * 4 + (threadIdx.x >> 6);
    int f = (threadIdx.x & 63) * 4;
    ushort4 b4 = *(const ushort4*)&UIb[(size_t)d * 256 + f];
    const ushort* bp = (const ushort*)&b4;
    float a0 = bf2f(bp[0]), a1 = bf2f(bp[1]), a2 = bf2f(bp[2]), a3 = bf2f(bp[3]);

    int st = offs[d], n = cnt[d];
    if (n > 0) {
        int   sc = srcs[st];
        float ac = vals[st];
        ushort4 vc = *(const ushort4*)&YJ[(size_t)sc * 256 + f];
        for (int e = 1; e < n; e++) {
            int   sn = srcs[st + e];
            float an = vals[st + e];
            ushort4 vn = *(const ushort4*)&YJ[(size_t)sn * 256 + f];
            const ushort* vp = (const ushort*)&vc;
            a0 += ac * bf2f(vp[0]); a1 += ac * bf2f(vp[1]);
            a2 += ac * bf2f(vp[2]); a3 += ac * bf2f(vp[3]);
            vc = vn; ac = an;
        }
        const ushort* vp = (const ushort*)&vc;
        a0 += ac * bf2f(vp[0]); a1 += ac * bf2f(vp[1]);
        a2 += ac * bf2f(vp[2]); a3 += ac * bf2f(vp[3]);
    }
    *(float4*)&out[(size_t)d * 256 + f] = make_float4(a0, a1, a2, a3);
}

// ---------------------------------------------------------------------------
// Host launcher
// ---------------------------------------------------------------------------
extern "C" void kernel_launch(void* const* d_in, const int* in_sizes, int n_in,
                              void* d_out, int out_size, void* d_ws, size_t ws_size,
                              hipStream_t stream)
{
    const float* x      = (const float*)d_in[0];
    const int*   up_row = (const int*)  d_in[1];
    const int*   up_col = (const int*)  d_in[2];
    const float* up_val = (const float*)d_in[3];
    const int*   e_src  = (const int*)  d_in[4];
    const int*   e_dst  = (const int*)  d_in[5];
    const float* adjv   = (const float*)d_in[6];
    const float* W_res  = (const float*)d_in[7];
    const float* b_res  = (const float*)d_in[8];
    const float* bn0_g  = (const float*)d_in[9];
    const float* bn0_b  = (const float*)d_in[10];
    const float* bn1_g  = (const float*)d_in[11];
    const float* bn1_b  = (const float*)d_in[12];
    const float* Ui0_W  = (const float*)d_in[13];
    const float* Ui0_b  = (const float*)d_in[14];
    const float* Uj0_W  = (const float*)d_in[15];
    const float* Uj0_b  = (const float*)d_in[16];
    const float* Ui1_W  = (const float*)d_in[17];
    const float* Ui1_b  = (const float*)d_in[18];
    const float* Uj1_W  = (const float*)d_in[19];
    const float* Uj1_b  = (const float*)d_in[20];

    float* out = (float*)d_out;

    // ---- workspace layout ----
    char* ws = (char*)d_ws;
    size_t off = 0;
    auto alloc = [&](size_t bytes) -> char* {
        char* p = ws + off;
        off = (off + bytes + 255) & ~(size_t)255;
        return p;
    };
    ushort* XW    = (ushort*)alloc((size_t)V_PREV * F_OUT * 2);   // 8.4 MB
    ushort* XNU   = (ushort*)alloc((size_t)V_PREV * 512 * 2);     // 16.8 MB
    ushort* UJb   = (ushort*)alloc((size_t)V_NEXT * F_OUT * 2);   // 33.6 MB (UIb aliases)
    ushort* X1    = (ushort*)alloc((size_t)V_NEXT * F_OUT * 2);   // 33.6 MB
    ushort* YJ    = (ushort*)alloc((size_t)V_NEXT * F_OUT * 2);   // 33.6 MB
    int*    cnt   = (int*)   alloc(V_NEXT * 4);
    int*    offs  = (int*)   alloc(V_NEXT * 4);
    int*    cursor= (int*)   alloc(V_NEXT * 4);
    int*    bsum  = (int*)   alloc(256 * 4);
    int*    boff  = (int*)   alloc(256 * 4);
    int*    srcs  = (int*)   alloc((size_t)N_EDGE * 4);
    float*  vals  = (float*) alloc((size_t)N_EDGE * 4);
    int*    colof = (int*)   alloc(V_NEXT * 4);
    float*  valof = (float*) alloc(V_NEXT * 4);
    ushort* WresT = (ushort*)alloc(256 * 512 * 2);
    ushort* W0t   = (ushort*)alloc(512 * 512 * 2);
    ushort* W1t   = (ushort*)alloc(512 * 256 * 2);
    float*  bias1 = (float*) alloc(512 * 4);
    float*  psum0 = (float*) alloc(128 * 512 * 4);
    float*  psq0  = (float*) alloc(128 * 512 * 4);
    float*  sc0   = (float*) alloc(512 * 4);
    float*  sh0   = (float*) alloc(512 * 4);
    float*  psum1 = (float*) alloc(512 * 256 * 4);
    float*  psq1  = (float*) alloc(512 * 256 * 4);
    float*  sc1   = (float*) alloc(256 * 4);
    float*  sh1   = (float*) alloc(256 * 4);
    (void)ws_size; (void)in_sizes; (void)n_in; (void)out_size;

    // alias: UIb reuses UJb storage (UJb dead after gather0; gemm1 runs later)
    ushort* UIb = UJb;

    // ---- weight prep + CSR build (independent of x) ----
    prep_weights_kernel<<<1024, 256, 0, stream>>>(W_res, Ui0_W, Uj0_W, Ui1_W, Uj1_W,
                                                  Ui1_b, Uj1_b, b_res,
                                                  WresT, W0t, W1t, bias1);
    hipMemsetAsync(cnt, 0, (size_t)V_NEXT * 4, stream);
    hist_kernel<<<N_EDGE / 256, 256, 0, stream>>>(e_dst, cnt);
    scan_block_kernel<<<256, 256, 0, stream>>>(cnt, offs, bsum);
    scan_top_kernel<<<1, 256, 0, stream>>>(bsum, boff);
    add_offs_kernel<<<256, 256, 0, stream>>>(offs, boff, cursor);
    fill_kernel<<<N_EDGE / 256, 256, 0, stream>>>(e_src, e_dst, adjv, cursor, srcs, vals);
    invert_up_kernel<<<NNZ_UP / 256, 256, 0, stream>>>(up_row, up_col, up_val, colof, valof);

    // ---- bn0 stats ----
    bn0_part_kernel<<<128, 256, 0, stream>>>(x, psum0, psq0);
    bn_finish_kernel<<<128, 256, 0, stream>>>(psum0, psq0, 128, 512, 1.0f / V_PREV,
                                              bn0_g, bn0_b, sc0, sh0);

    // ---- GEMM0 (fused bn0+relu+cast): XW [16384,256], XNU [16384,512] ----
    gemm0_fused_kernel<<<dim3(6, 128), 256, 0, stream>>>(x, WresT, W0t, sc0, sh0, XW, XNU);

    // ---- UJ table (upsample of Uj0 part) ----
    up_uj_kernel<<<NNZ_UP / 4, 256, 0, stream>>>(colof, valof, XNU, Uj0_b, UJb);

    // ---- ECC layer 0 aggregation ----
    gather0_kernel<<<V_NEXT / 4, 256, 0, stream>>>(offs, cnt, srcs, vals,
                                                   colof, valof, XNU, Ui0_b, UJb, X1);

    // ---- bn1 stats ----
    bn1_part_bf16_kernel<<<512, 256, 0, stream>>>(X1, psum1, psq1);
    bn_finish_kernel<<<64, 256, 0, stream>>>(psum1, psq1, 512, 256, 1.0f / V_NEXT,
                                             bn1_g, bn1_b, sc1, sh1);

    // ---- GEMM1 panel (fused bn1+relu; epilogue residual): YJ + UIb ----
    gemm1_panel_kernel<<<512, 256, 81920, stream>>>(X1, W1t, sc1, sh1, bias1,
                                                    colof, valof, XW, YJ, UIb);

    // ---- ECC layer 1 aggregation -> out ----
    gather1_kernel<<<V_NEXT / 4, 256, 0, stream>>>(offs, cnt, srcs, vals, YJ, UIb, out);
}